// Round 1
// baseline (1797.528 us; speedup 1.0000x reference)
//
#include <hip/hip_runtime.h>
#include <hip/hip_bf16.h>
#include <math.h>

// ---- problem constants ----
#define BB     16
#define HH     64
#define WWID   64
#define CCH    512
#define HEADS  16
#define NTOK   64     // tokens per window (8x8)
#define DDIM   32     // head dim
#define NWIN   64     // windows per image
#define LL     (HH*WWID)       // 4096
#define MTOT   (BB*LL)         // 65536 rows
#define BWIN   (BB*NWIN)       // 1024 windows
#define HIDN   2048
#define SHIFT_ 4

typedef unsigned short u16;
using bf16x8 = __attribute__((ext_vector_type(8))) short;   // 8 bf16
using f32x4  = __attribute__((ext_vector_type(4))) float;

__device__ __forceinline__ u16 f2bf(float f) {
  union { float f; unsigned u; } v; v.f = f;
  unsigned r = v.u + 0x7fffu + ((v.u >> 16) & 1u);   // RNE
  return (u16)(r >> 16);
}
__device__ __forceinline__ float bf2f(unsigned h) {
  union { unsigned u; float f; } v; v.u = h << 16;
  return v.f;
}

// shifted-window mapping: windowed token (b_, n) -> original row index in x
__device__ __forceinline__ int win2orig(int b_, int n) {
  int b = b_ >> 6, wi = b_ & 63;
  int hs = (wi >> 3) * 8 + (n >> 3);
  int ws = (wi & 7) * 8 + (n & 7);
  int hq = (hs + SHIFT_) & 63;
  int wq = (ws + SHIFT_) & 63;
  return b * LL + hq * WWID + wq;
}

// ---------------- tiny setup kernels ----------------
__global__ void cvt_k(const float* __restrict__ s, u16* __restrict__ d, int n) {
  int i = blockIdx.x * 256 + threadIdx.x;
  if (i < n) d[i] = f2bf(s[i]);
}

// table2[rr*16+h] = (relu(coords@w1.T+b1)@w2.T)[rr][h], rr in [0,225)
__global__ void cpb_k(const float* __restrict__ ct, const float* __restrict__ w1,
                      const float* __restrict__ b1, const float* __restrict__ w2,
                      float* __restrict__ t2) {
  int t = blockIdx.x * 256 + threadIdx.x;
  if (t >= 225 * 16) return;
  int rr = t >> 4, h = t & 15;
  float c0 = ct[rr * 2], c1 = ct[rr * 2 + 1];
  float acc = 0.f;
  for (int j = 0; j < 512; j++) {
    float hv = fmaxf(w1[j * 2] * c0 + w1[j * 2 + 1] * c1 + b1[j], 0.f);
    acc += hv * w2[h * 512 + j];
  }
  t2[t] = acc;
}

// bias16[h][n][m] = 16*sigmoid(table2[rpi[n,m]][h])
__global__ void bias_k(const float* __restrict__ t2, const int* __restrict__ rpi,
                       float* __restrict__ b16) {
  int t = blockIdx.x * 256 + threadIdx.x;   // h*4096 + n*64 + m, t < 65536
  int nm = t & 4095;
  int h = t >> 12;
  float v = t2[rpi[nm] * 16 + h];
  b16[t] = 16.0f / (1.0f + __expf(-v));
}

__global__ void scale_k(const float* __restrict__ ls, float* __restrict__ sc) {
  int t = threadIdx.x;
  if (t < HEADS) sc[t] = __expf(fminf(ls[t], 4.6051701859880914f)); // ln(100)
}

// in-place bf16 row normalization (rows of 32) for q and k
__global__ __launch_bounds__(256) void normqk_k(u16* __restrict__ buf, int nrows) {
  int r = blockIdx.x * 256 + threadIdx.x;
  if (r >= nrows) return;
  u16* p = buf + (size_t)r * DDIM;
  uint4 uu[4];
  uu[0] = *(const uint4*)p;        uu[1] = *(const uint4*)(p + 8);
  uu[2] = *(const uint4*)(p + 16); uu[3] = *(const uint4*)(p + 24);
  float f[32]; float s = 0.f;
  #pragma unroll
  for (int q = 0; q < 4; q++) {
    unsigned w[4] = {uu[q].x, uu[q].y, uu[q].z, uu[q].w};
    #pragma unroll
    for (int j = 0; j < 4; j++) {
      float lo = bf2f(w[j] & 0xffffu), hi = bf2f(w[j] >> 16);
      f[q * 8 + j * 2] = lo; f[q * 8 + j * 2 + 1] = hi;
      s += lo * lo + hi * hi;
    }
  }
  float inv = 1.f / fmaxf(sqrtf(s), 1e-12f);
  #pragma unroll
  for (int q = 0; q < 4; q++) {
    unsigned w[4];
    #pragma unroll
    for (int j = 0; j < 4; j++) {
      unsigned lo = f2bf(f[q * 8 + j * 2] * inv);
      unsigned hi = f2bf(f[q * 8 + j * 2 + 1] * inv);
      w[j] = lo | (hi << 16);
    }
    uint4 o = {w[0], w[1], w[2], w[3]};
    *(uint4*)(p + q * 8) = o;
  }
}

// ---------------- MFMA GEMM, 64x64 block tile, fused epilogues ----------------
// MODE 0: QKV  (A = x fp32, gathered via shift+window; epi: +q/v bias, scatter to [b_][h][n][d] bf16)
// MODE 1: proj (A bf16; epi: +proj_b, scatter fp32 to original token order)
// MODE 2: fc1  (A bf16; epi: +fc1_b, exact GELU, bf16 row-major ld=HIDN)
// MODE 3: fc2  (A bf16; epi: +fc2_b, bf16 row-major ld=CCH)
template<int MODE>
__global__ __launch_bounds__(256) void gemm_k(
    const float* __restrict__ Af, const u16* __restrict__ Ab,
    const u16* __restrict__ Bw, const float* __restrict__ bias,
    const float* __restrict__ qbias, const float* __restrict__ vbias,
    u16* __restrict__ qo, u16* __restrict__ ko, u16* __restrict__ vo,
    float* __restrict__ fo, u16* __restrict__ bo, int K)
{
  __shared__ u16 As[64 * 32];
  __shared__ u16 Bs[64 * 32];
  const int t = threadIdx.x;
  const int m0 = blockIdx.x * 64;
  const int n0 = blockIdx.y * 64;
  const int lane = t & 63;
  const int wv = t >> 6;
  const int wm = (wv & 1) * 32;
  const int wn = (wv >> 1) * 32;
  const int l15 = lane & 15;
  const int quad = lane >> 4;
  const int srow = t >> 2;         // 0..63
  const int scol = (t & 3) * 8;    // 0,8,16,24

  const float* arf = nullptr;
  const u16*  arb = nullptr;
  if (MODE == 0) {
    int m = m0 + srow;
    arf = Af + (size_t)win2orig(m >> 6, m & 63) * CCH;
  } else {
    arb = Ab + (size_t)(m0 + srow) * K;
  }
  const u16* brw = Bw + (size_t)(n0 + srow) * K;

  f32x4 acc00 = {0.f,0.f,0.f,0.f}, acc01 = {0.f,0.f,0.f,0.f};
  f32x4 acc10 = {0.f,0.f,0.f,0.f}, acc11 = {0.f,0.f,0.f,0.f};

  for (int k0 = 0; k0 < K; k0 += 32) {
    if (MODE == 0) {
      float4 p0 = *(const float4*)(arf + k0 + scol);
      float4 p1 = *(const float4*)(arf + k0 + scol + 4);
      u16* d = &As[srow * 32 + scol];
      d[0] = f2bf(p0.x); d[1] = f2bf(p0.y); d[2] = f2bf(p0.z); d[3] = f2bf(p0.w);
      d[4] = f2bf(p1.x); d[5] = f2bf(p1.y); d[6] = f2bf(p1.z); d[7] = f2bf(p1.w);
    } else {
      *(uint4*)&As[srow * 32 + scol] = *(const uint4*)(arb + k0 + scol);
    }
    *(uint4*)&Bs[srow * 32 + scol] = *(const uint4*)(brw + k0 + scol);
    __syncthreads();
    bf16x8 a0 = *(const bf16x8*)&As[(wm + l15) * 32 + quad * 8];
    bf16x8 a1 = *(const bf16x8*)&As[(wm + 16 + l15) * 32 + quad * 8];
    bf16x8 b0 = *(const bf16x8*)&Bs[(wn + l15) * 32 + quad * 8];
    bf16x8 b1 = *(const bf16x8*)&Bs[(wn + 16 + l15) * 32 + quad * 8];
    acc00 = __builtin_amdgcn_mfma_f32_16x16x32_bf16(a0, b0, acc00, 0, 0, 0);
    acc10 = __builtin_amdgcn_mfma_f32_16x16x32_bf16(a1, b0, acc10, 0, 0, 0);
    acc01 = __builtin_amdgcn_mfma_f32_16x16x32_bf16(a0, b1, acc01, 0, 0, 0);
    acc11 = __builtin_amdgcn_mfma_f32_16x16x32_bf16(a1, b1, acc11, 0, 0, 0);
    __syncthreads();
  }

  f32x4 accs[2][2] = {{acc00, acc01}, {acc10, acc11}};
  #pragma unroll
  for (int mt = 0; mt < 2; mt++)
  #pragma unroll
  for (int nt = 0; nt < 2; nt++)
  #pragma unroll
  for (int i = 0; i < 4; i++) {
    int gr = m0 + wm + mt * 16 + quad * 4 + i;   // row (C/D: row = quad*4+reg)
    int gc = n0 + wn + nt * 16 + l15;            // col (C/D: col = lane&15)
    float v = accs[mt][nt][i];
    if (MODE == 0) {
      int part = gc >> 9;        // 0=q 1=k 2=v
      int cc = gc & 511;
      if (part == 0) v += qbias[cc];
      else if (part == 2) v += vbias[cc];
      int b_ = gr >> 6, n = gr & 63;
      int hh = cc >> 5, dd = cc & 31;
      u16* dst = (part == 0) ? qo : (part == 1 ? ko : vo);
      dst[(((size_t)b_ * HEADS + hh) * NTOK + n) * DDIM + dd] = f2bf(v);
    } else if (MODE == 1) {
      v += bias[gc];
      fo[(size_t)win2orig(gr >> 6, gr & 63) * CCH + gc] = v;   // window reverse + unshift
    } else if (MODE == 2) {
      v += bias[gc];
      float g = 0.5f * v * (1.0f + erff(v * 0.70710678118654752f));
      bo[(size_t)gr * HIDN + gc] = f2bf(g);
    } else {
      v += bias[gc];
      bo[(size_t)gr * CCH + gc] = f2bf(v);
    }
  }
}

// ---------------- attention: one wave per (window, head) ----------------
__global__ __launch_bounds__(64) void attn_k(
    const u16* __restrict__ qb, const u16* __restrict__ kb, const u16* __restrict__ vb,
    const float* __restrict__ bias16, const float* __restrict__ scale,
    const float* __restrict__ amask, u16* __restrict__ attn_out)
{
  __shared__ float Smat[64][65];   // +1 pad: conflict-free per-row softmax
  __shared__ u16   Pmat[64][72];   // bf16 P (unnormalized), 16B-aligned rows
  __shared__ u16   vT[32][72];     // V transposed [d][tok]
  __shared__ float rsum[64];

  int bh = blockIdx.x;              // b_*16 + h
  int b_ = bh >> 4, h = bh & 15;
  int wi = b_ & 63;
  int lane = threadIdx.x;
  int l15 = lane & 15, quad = lane >> 4;
  const u16* qs = qb + (size_t)bh * (NTOK * DDIM);
  const u16* ks = kb + (size_t)bh * (NTOK * DDIM);
  const u16* vs = vb + (size_t)bh * (NTOK * DDIM);

  // fragments straight from global (slice is 4KB contiguous, L1-hot)
  bf16x8 qf[4], kf[4];
  #pragma unroll
  for (int mt = 0; mt < 4; mt++) {
    qf[mt] = *(const bf16x8*)(qs + (mt * 16 + l15) * DDIM + quad * 8);
    kf[mt] = *(const bf16x8*)(ks + (mt * 16 + l15) * DDIM + quad * 8);
  }
  // S = qn @ kn^T (raw logits, pre-scale)
  #pragma unroll
  for (int mt = 0; mt < 4; mt++)
    #pragma unroll
    for (int nt = 0; nt < 4; nt++) {
      f32x4 c = {0.f,0.f,0.f,0.f};
      c = __builtin_amdgcn_mfma_f32_16x16x32_bf16(qf[mt], kf[nt], c, 0, 0, 0);
      #pragma unroll
      for (int i = 0; i < 4; i++)
        Smat[mt * 16 + quad * 4 + i][nt * 16 + l15] = c[i];
    }
  // stage V^T
  #pragma unroll
  for (int d8 = 0; d8 < 4; d8++) {
    bf16x8 vv = *(const bf16x8*)(vs + lane * DDIM + d8 * 8);
    #pragma unroll
    for (int j = 0; j < 8; j++) vT[d8 * 8 + j][lane] = (u16)vv[j];
  }
  __syncthreads();

  // softmax: lane = row
  {
    int r = lane;
    const float* brow = bias16 + ((size_t)h * 64 + r) * 64;
    const float* mrow = amask + ((size_t)wi * 64 + r) * 64;
    float sc = scale[h];
    float vrow[64];
    float mx = -1e30f;
    #pragma unroll
    for (int c = 0; c < 64; c++) {
      float vv = Smat[r][c] * sc + brow[c] + mrow[c];
      vrow[c] = vv;
      mx = fmaxf(mx, vv);
    }
    float sum = 0.f;
    #pragma unroll
    for (int c = 0; c < 64; c++) {
      float p = __expf(vrow[c] - mx);
      sum += p;
      Pmat[r][c] = f2bf(p);
    }
    rsum[r] = 1.f / sum;
  }
  __syncthreads();

  // O = P @ V   (1/sum folded into epilogue)
  f32x4 oacc[4][2] = {};
  #pragma unroll
  for (int ks2 = 0; ks2 < 2; ks2++) {
    bf16x8 pf[4], vf[2];
    #pragma unroll
    for (int mt = 0; mt < 4; mt++)
      pf[mt] = *(const bf16x8*)&Pmat[mt * 16 + l15][ks2 * 32 + quad * 8];
    #pragma unroll
    for (int nt = 0; nt < 2; nt++)
      vf[nt] = *(const bf16x8*)&vT[nt * 16 + l15][ks2 * 32 + quad * 8];
    #pragma unroll
    for (int mt = 0; mt < 4; mt++)
      #pragma unroll
      for (int nt = 0; nt < 2; nt++)
        oacc[mt][nt] = __builtin_amdgcn_mfma_f32_16x16x32_bf16(pf[mt], vf[nt], oacc[mt][nt], 0, 0, 0);
  }
  #pragma unroll
  for (int mt = 0; mt < 4; mt++)
    #pragma unroll
    for (int nt = 0; nt < 2; nt++)
      #pragma unroll
      for (int i = 0; i < 4; i++) {
        int n = mt * 16 + quad * 4 + i;
        int d = nt * 16 + l15;
        float val = oacc[mt][nt][i] * rsum[n];
        attn_out[(size_t)(b_ * 64 + n) * CCH + h * DDIM + d] = f2bf(val);
      }
}

// ---------------- LayerNorm + residual kernels (one wave per row) ----------------
__global__ __launch_bounds__(256) void ln_res_k(
    const float* __restrict__ xin, const float* __restrict__ pin,
    const float* __restrict__ gam, const float* __restrict__ bet,
    float* __restrict__ x1f, u16* __restrict__ x1b)
{
  int row = blockIdx.x * 4 + (threadIdx.x >> 6);
  int lane = threadIdx.x & 63;
  size_t base = (size_t)row * CCH + lane * 8;
  const float* pr = pin + base;
  const float* xr = xin + base;
  float4 v0 = *(const float4*)pr;
  float4 v1 = *(const float4*)(pr + 4);
  float pv[8] = {v0.x, v0.y, v0.z, v0.w, v1.x, v1.y, v1.z, v1.w};
  float s = 0.f, sq = 0.f;
  #pragma unroll
  for (int j = 0; j < 8; j++) { s += pv[j]; sq += pv[j] * pv[j]; }
  #pragma unroll
  for (int o = 32; o > 0; o >>= 1) { s += __shfl_xor(s, o, 64); sq += __shfl_xor(sq, o, 64); }
  float mean = s * (1.0f / 512.0f);
  float var = sq * (1.0f / 512.0f) - mean * mean;
  float rstd = rsqrtf(var + 1e-5f);
  #pragma unroll
  for (int j = 0; j < 8; j++) {
    int c = lane * 8 + j;
    float val = xr[j] + (pv[j] - mean) * rstd * gam[c] + bet[c];
    x1f[base + j] = val;
    x1b[base + j] = f2bf(val);
  }
}

__global__ __launch_bounds__(256) void ln_fin_k(
    const u16* __restrict__ mlp, const float* __restrict__ gam,
    const float* __restrict__ bet, float* __restrict__ io)
{
  int row = blockIdx.x * 4 + (threadIdx.x >> 6);
  int lane = threadIdx.x & 63;
  size_t base = (size_t)row * CCH + lane * 8;
  uint4 u = *(const uint4*)(mlp + base);
  unsigned w[4] = {u.x, u.y, u.z, u.w};
  float pv[8];
  #pragma unroll
  for (int j = 0; j < 4; j++) {
    pv[j * 2] = bf2f(w[j] & 0xffffu);
    pv[j * 2 + 1] = bf2f(w[j] >> 16);
  }
  float s = 0.f, sq = 0.f;
  #pragma unroll
  for (int j = 0; j < 8; j++) { s += pv[j]; sq += pv[j] * pv[j]; }
  #pragma unroll
  for (int o = 32; o > 0; o >>= 1) { s += __shfl_xor(s, o, 64); sq += __shfl_xor(sq, o, 64); }
  float mean = s * (1.0f / 512.0f);
  float var = sq * (1.0f / 512.0f) - mean * mean;
  float rstd = rsqrtf(var + 1e-5f);
  #pragma unroll
  for (int j = 0; j < 8; j++) {
    int c = lane * 8 + j;
    io[base + j] = io[base + j] + (pv[j] - mean) * rstd * gam[c] + bet[c];
  }
}

// ---------------- launcher ----------------
// ws layout (bytes), regions reused across phases (~326 MiB total):
//  R0 @0      (192Mi): q/k/v bf16 -> proj_out fp32 (128Mi) -> hidden bf16 half (128Mi)
//  R1 @192Mi  ( 64Mi): attn_out bf16 -> mlp_out bf16
//  R2 @256Mi  ( 64Mi): x1 bf16
//  R3 @320Mi  ( ~7Mi): bf16 weights, cpb table, bias16, scale
#define OFF_Q     ((size_t)0)
#define OFF_K     ((size_t)67108864)
#define OFF_V     ((size_t)134217728)
#define OFF_ATTN  ((size_t)201326592)
#define OFF_X1B   ((size_t)268435456)
#define OFF_WQKV  ((size_t)335544320)
#define OFF_WPROJ ((size_t)337117184)
#define OFF_WFC1  ((size_t)337641472)
#define OFF_WFC2  ((size_t)339738624)
#define OFF_T2    ((size_t)341835776)
#define OFF_B16   ((size_t)341852160)
#define OFF_SC    ((size_t)342114304)

extern "C" void kernel_launch(void* const* d_in, const int* in_sizes, int n_in,
                              void* d_out, int out_size, void* d_ws, size_t ws_size,
                              hipStream_t stream) {
  const float* x        = (const float*)d_in[0];
  const float* qkv_w    = (const float*)d_in[1];
  const float* q_bias   = (const float*)d_in[2];
  const float* v_bias   = (const float*)d_in[3];
  const float* lscale   = (const float*)d_in[4];
  const float* cpb_w1   = (const float*)d_in[5];
  const float* cpb_b1   = (const float*)d_in[6];
  const float* cpb_w2   = (const float*)d_in[7];
  const float* proj_w   = (const float*)d_in[8];
  const float* proj_b   = (const float*)d_in[9];
  const float* n1g      = (const float*)d_in[10];
  const float* n1b      = (const float*)d_in[11];
  const float* n2g      = (const float*)d_in[12];
  const float* n2b      = (const float*)d_in[13];
  const float* fc1_w    = (const float*)d_in[14];
  const float* fc1_b    = (const float*)d_in[15];
  const float* fc2_w    = (const float*)d_in[16];
  const float* fc2_b    = (const float*)d_in[17];
  const float* ctab     = (const float*)d_in[18];
  const float* amask    = (const float*)d_in[19];
  const int*   rpi      = (const int*)d_in[20];

  char* ws = (char*)d_ws;
  float* outp = (float*)d_out;

  u16*   q_buf    = (u16*)(ws + OFF_Q);
  u16*   k_buf    = (u16*)(ws + OFF_K);
  u16*   v_buf    = (u16*)(ws + OFF_V);
  float* proj_out = (float*)(ws + OFF_Q);     // reuse R0
  u16*   hid      = (u16*)(ws + OFF_Q);       // reuse R0 (half-batch)
  u16*   attn_out = (u16*)(ws + OFF_ATTN);
  u16*   mlp_out  = (u16*)(ws + OFF_ATTN);    // reuse R1
  u16*   x1b      = (u16*)(ws + OFF_X1B);
  u16*   wqkv     = (u16*)(ws + OFF_WQKV);
  u16*   wproj    = (u16*)(ws + OFF_WPROJ);
  u16*   wfc1     = (u16*)(ws + OFF_WFC1);
  u16*   wfc2     = (u16*)(ws + OFF_WFC2);
  float* t2       = (float*)(ws + OFF_T2);
  float* b16      = (float*)(ws + OFF_B16);
  float* scbuf    = (float*)(ws + OFF_SC);

  // setup: weight conversion + CPB bias + scale
  cvt_k<<<(1536 * 512 + 255) / 256, 256, 0, stream>>>(qkv_w, wqkv, 1536 * 512);
  cvt_k<<<(512 * 512 + 255) / 256, 256, 0, stream>>>(proj_w, wproj, 512 * 512);
  cvt_k<<<(2048 * 512 + 255) / 256, 256, 0, stream>>>(fc1_w, wfc1, 2048 * 512);
  cvt_k<<<(512 * 2048 + 255) / 256, 256, 0, stream>>>(fc2_w, wfc2, 512 * 2048);
  cpb_k<<<15, 256, 0, stream>>>(ctab, cpb_w1, cpb_b1, cpb_w2, t2);
  bias_k<<<256, 256, 0, stream>>>(t2, rpi, b16);
  scale_k<<<1, 64, 0, stream>>>(lscale, scbuf);

  // QKV (shift+window gather fused) -> q/k/v [b_][h][n][d] bf16
  gemm_k<0><<<dim3(MTOT / 64, 1536 / 64), 256, 0, stream>>>(
      x, nullptr, wqkv, nullptr, q_bias, v_bias, q_buf, k_buf, v_buf, nullptr, nullptr, 512);
  // cosine-normalize q and k (contiguous regions -> one launch)
  normqk_k<<<(2 * BWIN * HEADS * NTOK + 255) / 256, 256, 0, stream>>>(q_buf, 2 * BWIN * HEADS * NTOK);
  // attention
  attn_k<<<BWIN * HEADS, 64, 0, stream>>>(q_buf, k_buf, v_buf, b16, scbuf, amask, attn_out);
  // proj (window reverse fused) -> proj_out fp32, original token order
  gemm_k<1><<<dim3(MTOT / 64, 512 / 64), 256, 0, stream>>>(
      nullptr, attn_out, wproj, proj_b, nullptr, nullptr, nullptr, nullptr, nullptr, proj_out, nullptr, 512);
  // x1 = x + LN1(proj_out)  -> d_out (fp32) + x1b (bf16)
  ln_res_k<<<MTOT / 4, 256, 0, stream>>>(x, proj_out, n1g, n1b, outp, x1b);
  // MLP in two row-halves (hidden buffer reuse, 128 MiB)
  for (int half = 0; half < 2; half++) {
    const u16* a1 = x1b + (size_t)half * (MTOT / 2) * CCH;
    u16* m1 = mlp_out + (size_t)half * (MTOT / 2) * CCH;
    gemm_k<2><<<dim3(MTOT / 2 / 64, HIDN / 64), 256, 0, stream>>>(
        nullptr, a1, wfc1, fc1_b, nullptr, nullptr, nullptr, nullptr, nullptr, nullptr, hid, 512);
    gemm_k<3><<<dim3(MTOT / 2 / 64, 512 / 64), 256, 0, stream>>>(
        nullptr, hid, wfc2, fc2_b, nullptr, nullptr, nullptr, nullptr, nullptr, nullptr, m1, 2048);
  }
  // out = x1 + LN2(mlp)
  ln_fin_k<<<MTOT / 4, 256, 0, stream>>>(mlp_out, n2g, n2b, outp);
}

// Round 2
// 1362.624 us; speedup vs baseline: 1.3192x; 1.3192x over previous
//
#include <hip/hip_runtime.h>
#include <hip/hip_bf16.h>
#include <math.h>

// ---- problem constants ----
#define BB     16
#define HH     64
#define WWID   64
#define CCH    512
#define HEADS  16
#define NTOK   64     // tokens per window (8x8)
#define DDIM   32     // head dim
#define NWIN   64     // windows per image
#define LL     (HH*WWID)       // 4096
#define MTOT   (BB*LL)         // 65536 rows
#define BWIN   (BB*NWIN)       // 1024 windows
#define HIDN   2048
#define SHIFT_ 4

typedef unsigned short u16;
using bf16x8 = __attribute__((ext_vector_type(8))) short;   // 8 bf16
using f32x4  = __attribute__((ext_vector_type(4))) float;

__device__ __forceinline__ u16 f2bf(float f) {
  union { float f; unsigned u; } v; v.f = f;
  unsigned r = v.u + 0x7fffu + ((v.u >> 16) & 1u);   // RNE
  return (u16)(r >> 16);
}
__device__ __forceinline__ float bf2f(unsigned h) {
  union { unsigned u; float f; } v; v.u = h << 16;
  return v.f;
}

// async global->LDS, 16B per lane; lds dst = wave-uniform base + lane*16
__device__ __forceinline__ void gload16(const void* g, void* l) {
  __builtin_amdgcn_global_load_lds((const __attribute__((address_space(1))) void*)g,
                                   (__attribute__((address_space(3))) void*)l, 16, 0, 0);
}

// shifted-window mapping: windowed token (b_, n) -> original row index in x
__device__ __forceinline__ int win2orig(int b_, int n) {
  int b = b_ >> 6, wi = b_ & 63;
  int hs = (wi >> 3) * 8 + (n >> 3);
  int ws = (wi & 7) * 8 + (n & 7);
  int hq = (hs + SHIFT_) & 63;
  int wq = (ws + SHIFT_) & 63;
  return b * LL + hq * WWID + wq;
}

// ---------------- tiny setup kernels ----------------
__global__ void cvt_k(const float* __restrict__ s, u16* __restrict__ d, int n) {
  int i = blockIdx.x * 256 + threadIdx.x;
  if (i < n) d[i] = f2bf(s[i]);
}

__global__ void cpb_k(const float* __restrict__ ct, const float* __restrict__ w1,
                      const float* __restrict__ b1, const float* __restrict__ w2,
                      float* __restrict__ t2) {
  int t = blockIdx.x * 256 + threadIdx.x;
  if (t >= 225 * 16) return;
  int rr = t >> 4, h = t & 15;
  float c0 = ct[rr * 2], c1 = ct[rr * 2 + 1];
  float acc = 0.f;
  for (int j = 0; j < 512; j++) {
    float hv = fmaxf(w1[j * 2] * c0 + w1[j * 2 + 1] * c1 + b1[j], 0.f);
    acc += hv * w2[h * 512 + j];
  }
  t2[t] = acc;
}

__global__ void bias_k(const float* __restrict__ t2, const int* __restrict__ rpi,
                       float* __restrict__ b16) {
  int t = blockIdx.x * 256 + threadIdx.x;   // h*4096 + n*64 + m
  int nm = t & 4095;
  int h = t >> 12;
  float v = t2[rpi[nm] * 16 + h];
  b16[t] = 16.0f / (1.0f + __expf(-v));
}

__global__ void scale_k(const float* __restrict__ ls, float* __restrict__ sc) {
  int t = threadIdx.x;
  if (t < HEADS) sc[t] = __expf(fminf(ls[t], 4.6051701859880914f)); // ln(100)
}

// x (fp32) -> xw (bf16) in shifted-window token order [b_*64+n][512]
__global__ __launch_bounds__(256) void xw_k(const float* __restrict__ x, u16* __restrict__ xw) {
  int t = blockIdx.x * 256 + threadIdx.x;   // each handles 8 elements
  int row = t >> 6;
  int col = (t & 63) * 8;
  const float* src = x + (size_t)win2orig(row >> 6, row & 63) * CCH + col;
  float4 a = *(const float4*)src;
  float4 b = *(const float4*)(src + 4);
  u16 o[8] = {f2bf(a.x), f2bf(a.y), f2bf(a.z), f2bf(a.w),
              f2bf(b.x), f2bf(b.y), f2bf(b.z), f2bf(b.w)};
  *(uint4*)(xw + (size_t)row * CCH + col) = *(const uint4*)o;
}

// ---------------- MFMA GEMM, 128x128 tile, global_load_lds staging ----------------
// A bf16 row-major [M][K], B bf16 row-major [N][K] (i.e. computes A @ B^T).
// MODE 0: QKV  (epi: +q/v bias, scatter to [b_][h][n][d] bf16)
// MODE 1: proj (epi: +proj_b, scatter fp32 to original token order)
// MODE 2: fc1  (epi: +fc1_b, exact GELU, bf16 row-major ld=HIDN)
// MODE 3: fc2  (epi: +fc2_b, bf16 row-major ld=CCH)
template<int MODE>
__global__ __launch_bounds__(256) void gemm128_k(
    const u16* __restrict__ A, const u16* __restrict__ Bw,
    const float* __restrict__ bias,
    const float* __restrict__ qbias, const float* __restrict__ vbias,
    u16* __restrict__ qo, u16* __restrict__ ko, u16* __restrict__ vo,
    float* __restrict__ fo, u16* __restrict__ bo, int K)
{
  __shared__ __align__(16) u16 As[128 * 32];
  __shared__ __align__(16) u16 Bs[128 * 32];
  const int t = threadIdx.x;
  const int n0 = blockIdx.x * 128;   // N fast-varying: blocks sharing A-tile adjacent
  const int m0 = blockIdx.y * 128;
  const int lane = t & 63;
  const int wv = t >> 6;            // wave 0..3
  const int wm = (wv & 1) * 64;
  const int wn = (wv >> 1) * 64;
  const int l15 = lane & 15;
  const int quad = lane >> 4;

  // staging: thread t loads 16B (8 bf16): row t>>2 (+64 for issue 1), col (t&3)*8
  const u16* ag = A  + (size_t)(m0 + (t >> 2)) * K + (t & 3) * 8;
  const u16* bg = Bw + (size_t)(n0 + (t >> 2)) * K + (t & 3) * 8;
  char* asl0 = (char*)As + wv * 1024;
  char* asl1 = (char*)As + 4096 + wv * 1024;
  char* bsl0 = (char*)Bs + wv * 1024;
  char* bsl1 = (char*)Bs + 4096 + wv * 1024;

  f32x4 acc[4][4] = {};

  for (int k0 = 0; k0 < K; k0 += 32) {
    gload16(ag + k0, asl0);
    gload16(ag + (size_t)64 * K + k0, asl1);
    gload16(bg + k0, bsl0);
    gload16(bg + (size_t)64 * K + k0, bsl1);
    __syncthreads();
    bf16x8 af[4], bf[4];
    #pragma unroll
    for (int mt = 0; mt < 4; mt++)
      af[mt] = *(const bf16x8*)&As[(wm + mt * 16 + l15) * 32 + quad * 8];
    #pragma unroll
    for (int nt = 0; nt < 4; nt++)
      bf[nt] = *(const bf16x8*)&Bs[(wn + nt * 16 + l15) * 32 + quad * 8];
    #pragma unroll
    for (int mt = 0; mt < 4; mt++)
      #pragma unroll
      for (int nt = 0; nt < 4; nt++)
        acc[mt][nt] = __builtin_amdgcn_mfma_f32_16x16x32_bf16(af[mt], bf[nt], acc[mt][nt], 0, 0, 0);
    __syncthreads();
  }

  // epilogue; C/D layout: row = quad*4+reg, col = lane&15
  const int part = n0 >> 9;           // MODE 0: q/k/v part (tile never spans parts)
  #pragma unroll
  for (int mt = 0; mt < 4; mt++)
    #pragma unroll
    for (int nt = 0; nt < 4; nt++)
      #pragma unroll
      for (int i = 0; i < 4; i++) {
        int gr = m0 + wm + mt * 16 + quad * 4 + i;
        int gc = n0 + wn + nt * 16 + l15;
        float v = acc[mt][nt][i];
        if (MODE == 0) {
          int cc = gc & 511;
          if (part == 0) v += qbias[cc];
          else if (part == 2) v += vbias[cc];
          int b_ = gr >> 6, n = gr & 63;
          int hh = cc >> 5, dd = cc & 31;
          u16* dst = (part == 0) ? qo : (part == 1 ? ko : vo);
          dst[(((size_t)b_ * HEADS + hh) * NTOK + n) * DDIM + dd] = f2bf(v);
        } else if (MODE == 1) {
          v += bias[gc];
          fo[(size_t)win2orig(gr >> 6, gr & 63) * CCH + gc] = v;  // window reverse + unshift
        } else if (MODE == 2) {
          v += bias[gc];
          float g = 0.5f * v * (1.0f + erff(v * 0.70710678118654752f));
          bo[(size_t)gr * HIDN + gc] = f2bf(g);
        } else {
          v += bias[gc];
          bo[(size_t)gr * CCH + gc] = f2bf(v);
        }
      }
}

// ---------------- attention: one wave per (window, head), fused q/k norm ----------------
__global__ __launch_bounds__(64) void attn_k(
    const u16* __restrict__ qb, const u16* __restrict__ kb, const u16* __restrict__ vb,
    const float* __restrict__ bias16, const float* __restrict__ scale,
    const float* __restrict__ amask, u16* __restrict__ attn_out)
{
  __shared__ float Smat[64][65];
  __shared__ u16   Pmat[64][72];
  __shared__ u16   vT[32][72];
  __shared__ float rsum[64];

  int bh = blockIdx.x;              // b_*16 + h
  int b_ = bh >> 4, h = bh & 15;
  int wi = b_ & 63;
  int lane = threadIdx.x;
  int l15 = lane & 15, quad = lane >> 4;
  const u16* qs = qb + (size_t)bh * (NTOK * DDIM);
  const u16* ks = kb + (size_t)bh * (NTOK * DDIM);
  const u16* vs = vb + (size_t)bh * (NTOK * DDIM);

  bf16x8 qf[4], kf[4];
  #pragma unroll
  for (int mt = 0; mt < 4; mt++) {
    qf[mt] = *(const bf16x8*)(qs + (mt * 16 + l15) * DDIM + quad * 8);
    kf[mt] = *(const bf16x8*)(ks + (mt * 16 + l15) * DDIM + quad * 8);
  }
  // fused cosine normalization: lanes {l15, l15+16, l15+32, l15+48} share a row
  #pragma unroll
  for (int mt = 0; mt < 4; mt++) {
    float sq = 0.f, sk = 0.f;
    #pragma unroll
    for (int j = 0; j < 8; j++) {
      float a = bf2f((u16)qf[mt][j]); sq += a * a;
      float b = bf2f((u16)kf[mt][j]); sk += b * b;
    }
    sq += __shfl_xor(sq, 16); sq += __shfl_xor(sq, 32);
    sk += __shfl_xor(sk, 16); sk += __shfl_xor(sk, 32);
    float iq = 1.f / fmaxf(sqrtf(sq), 1e-12f);
    float ik = 1.f / fmaxf(sqrtf(sk), 1e-12f);
    #pragma unroll
    for (int j = 0; j < 8; j++) {
      qf[mt][j] = (short)f2bf(bf2f((u16)qf[mt][j]) * iq);
      kf[mt][j] = (short)f2bf(bf2f((u16)kf[mt][j]) * ik);
    }
  }
  // S = qn @ kn^T
  #pragma unroll
  for (int mt = 0; mt < 4; mt++)
    #pragma unroll
    for (int nt = 0; nt < 4; nt++) {
      f32x4 c = {0.f, 0.f, 0.f, 0.f};
      c = __builtin_amdgcn_mfma_f32_16x16x32_bf16(qf[mt], kf[nt], c, 0, 0, 0);
      #pragma unroll
      for (int i = 0; i < 4; i++)
        Smat[mt * 16 + quad * 4 + i][nt * 16 + l15] = c[i];
    }
  // stage V^T
  #pragma unroll
  for (int d8 = 0; d8 < 4; d8++) {
    bf16x8 vv = *(const bf16x8*)(vs + lane * DDIM + d8 * 8);
    #pragma unroll
    for (int j = 0; j < 8; j++) vT[d8 * 8 + j][lane] = (u16)vv[j];
  }
  __syncthreads();

  // softmax: lane = row
  {
    int r = lane;
    const float* brow = bias16 + ((size_t)h * 64 + r) * 64;
    const float* mrow = amask + ((size_t)wi * 64 + r) * 64;
    float sc = scale[h];
    float vrow[64];
    float mx = -1e30f;
    #pragma unroll
    for (int c = 0; c < 64; c++) {
      float vv = Smat[r][c] * sc + brow[c] + mrow[c];
      vrow[c] = vv;
      mx = fmaxf(mx, vv);
    }
    float sum = 0.f;
    #pragma unroll
    for (int c = 0; c < 64; c++) {
      float p = __expf(vrow[c] - mx);
      sum += p;
      Pmat[r][c] = f2bf(p);
    }
    rsum[r] = 1.f / sum;
  }
  __syncthreads();

  // O = P @ V
  f32x4 oacc[4][2] = {};
  #pragma unroll
  for (int ks2 = 0; ks2 < 2; ks2++) {
    bf16x8 pf[4], vf[2];
    #pragma unroll
    for (int mt = 0; mt < 4; mt++)
      pf[mt] = *(const bf16x8*)&Pmat[mt * 16 + l15][ks2 * 32 + quad * 8];
    #pragma unroll
    for (int nt = 0; nt < 2; nt++)
      vf[nt] = *(const bf16x8*)&vT[nt * 16 + l15][ks2 * 32 + quad * 8];
    #pragma unroll
    for (int mt = 0; mt < 4; mt++)
      #pragma unroll
      for (int nt = 0; nt < 2; nt++)
        oacc[mt][nt] = __builtin_amdgcn_mfma_f32_16x16x32_bf16(pf[mt], vf[nt], oacc[mt][nt], 0, 0, 0);
  }
  #pragma unroll
  for (int mt = 0; mt < 4; mt++)
    #pragma unroll
    for (int nt = 0; nt < 2; nt++)
      #pragma unroll
      for (int i = 0; i < 4; i++) {
        int n = mt * 16 + quad * 4 + i;
        int d = nt * 16 + l15;
        float val = oacc[mt][nt][i] * rsum[n];
        attn_out[(size_t)(b_ * 64 + n) * CCH + h * DDIM + d] = f2bf(val);
      }
}

// ---------------- LayerNorm + residual kernels (one wave per row) ----------------
__global__ __launch_bounds__(256) void ln_res_k(
    const float* __restrict__ xin, const float* __restrict__ pin,
    const float* __restrict__ gam, const float* __restrict__ bet,
    float* __restrict__ x1f, u16* __restrict__ x1b)
{
  int row = blockIdx.x * 4 + (threadIdx.x >> 6);
  int lane = threadIdx.x & 63;
  size_t base = (size_t)row * CCH + lane * 8;
  const float* pr = pin + base;
  const float* xr = xin + base;
  float4 v0 = *(const float4*)pr;
  float4 v1 = *(const float4*)(pr + 4);
  float pv[8] = {v0.x, v0.y, v0.z, v0.w, v1.x, v1.y, v1.z, v1.w};
  float s = 0.f, sq = 0.f;
  #pragma unroll
  for (int j = 0; j < 8; j++) { s += pv[j]; sq += pv[j] * pv[j]; }
  #pragma unroll
  for (int o = 32; o > 0; o >>= 1) { s += __shfl_xor(s, o, 64); sq += __shfl_xor(sq, o, 64); }
  float mean = s * (1.0f / 512.0f);
  float var = sq * (1.0f / 512.0f) - mean * mean;
  float rstd = rsqrtf(var + 1e-5f);
  #pragma unroll
  for (int j = 0; j < 8; j++) {
    int c = lane * 8 + j;
    float val = xr[j] + (pv[j] - mean) * rstd * gam[c] + bet[c];
    x1f[base + j] = val;
    x1b[base + j] = f2bf(val);
  }
}

__global__ __launch_bounds__(256) void ln_fin_k(
    const u16* __restrict__ mlp, const float* __restrict__ gam,
    const float* __restrict__ bet, float* __restrict__ io)
{
  int row = blockIdx.x * 4 + (threadIdx.x >> 6);
  int lane = threadIdx.x & 63;
  size_t base = (size_t)row * CCH + lane * 8;
  uint4 u = *(const uint4*)(mlp + base);
  unsigned w[4] = {u.x, u.y, u.z, u.w};
  float pv[8];
  #pragma unroll
  for (int j = 0; j < 4; j++) {
    pv[j * 2] = bf2f(w[j] & 0xffffu);
    pv[j * 2 + 1] = bf2f(w[j] >> 16);
  }
  float s = 0.f, sq = 0.f;
  #pragma unroll
  for (int j = 0; j < 8; j++) { s += pv[j]; sq += pv[j] * pv[j]; }
  #pragma unroll
  for (int o = 32; o > 0; o >>= 1) { s += __shfl_xor(s, o, 64); sq += __shfl_xor(sq, o, 64); }
  float mean = s * (1.0f / 512.0f);
  float var = sq * (1.0f / 512.0f) - mean * mean;
  float rstd = rsqrtf(var + 1e-5f);
  #pragma unroll
  for (int j = 0; j < 8; j++) {
    int c = lane * 8 + j;
    io[base + j] = io[base + j] + (pv[j] - mean) * rstd * gam[c] + bet[c];
  }
}

// ---------------- launcher ----------------
// ws layout (bytes), regions reused across phases (~326 MiB total):
//  R0 @0      (192Mi): q/k/v bf16 -> proj_out fp32 (128Mi) -> hidden bf16 half (128Mi)
//  R1 @192Mi  ( 64Mi): xw bf16 -> attn_out bf16 -> mlp_out bf16
//  R2 @256Mi  ( 64Mi): x1 bf16
//  R3 @320Mi  ( ~7Mi): bf16 weights, cpb table, bias16, scale
#define OFF_Q     ((size_t)0)
#define OFF_K     ((size_t)67108864)
#define OFF_V     ((size_t)134217728)
#define OFF_ATTN  ((size_t)201326592)
#define OFF_X1B   ((size_t)268435456)
#define OFF_WQKV  ((size_t)335544320)
#define OFF_WPROJ ((size_t)337117184)
#define OFF_WFC1  ((size_t)337641472)
#define OFF_WFC2  ((size_t)339738624)
#define OFF_T2    ((size_t)341835776)
#define OFF_B16   ((size_t)341852160)
#define OFF_SC    ((size_t)342114304)

extern "C" void kernel_launch(void* const* d_in, const int* in_sizes, int n_in,
                              void* d_out, int out_size, void* d_ws, size_t ws_size,
                              hipStream_t stream) {
  const float* x        = (const float*)d_in[0];
  const float* qkv_w    = (const float*)d_in[1];
  const float* q_bias   = (const float*)d_in[2];
  const float* v_bias   = (const float*)d_in[3];
  const float* lscale   = (const float*)d_in[4];
  const float* cpb_w1   = (const float*)d_in[5];
  const float* cpb_b1   = (const float*)d_in[6];
  const float* cpb_w2   = (const float*)d_in[7];
  const float* proj_w   = (const float*)d_in[8];
  const float* proj_b   = (const float*)d_in[9];
  const float* n1g      = (const float*)d_in[10];
  const float* n1b      = (const float*)d_in[11];
  const float* n2g      = (const float*)d_in[12];
  const float* n2b      = (const float*)d_in[13];
  const float* fc1_w    = (const float*)d_in[14];
  const float* fc1_b    = (const float*)d_in[15];
  const float* fc2_w    = (const float*)d_in[16];
  const float* fc2_b    = (const float*)d_in[17];
  const float* ctab     = (const float*)d_in[18];
  const float* amask    = (const float*)d_in[19];
  const int*   rpi      = (const int*)d_in[20];

  char* ws = (char*)d_ws;
  float* outp = (float*)d_out;

  u16*   q_buf    = (u16*)(ws + OFF_Q);
  u16*   k_buf    = (u16*)(ws + OFF_K);
  u16*   v_buf    = (u16*)(ws + OFF_V);
  float* proj_out = (float*)(ws + OFF_Q);     // reuse R0
  u16*   hid      = (u16*)(ws + OFF_Q);       // reuse R0 (half-batch)
  u16*   xw       = (u16*)(ws + OFF_ATTN);    // R1 (dead after QKV gemm)
  u16*   attn_out = (u16*)(ws + OFF_ATTN);
  u16*   mlp_out  = (u16*)(ws + OFF_ATTN);
  u16*   x1b      = (u16*)(ws + OFF_X1B);
  u16*   wqkv     = (u16*)(ws + OFF_WQKV);
  u16*   wproj    = (u16*)(ws + OFF_WPROJ);
  u16*   wfc1     = (u16*)(ws + OFF_WFC1);
  u16*   wfc2     = (u16*)(ws + OFF_WFC2);
  float* t2       = (float*)(ws + OFF_T2);
  float* b16      = (float*)(ws + OFF_B16);
  float* scbuf    = (float*)(ws + OFF_SC);

  // setup: weight conversion + CPB bias + scale
  cvt_k<<<(1536 * 512 + 255) / 256, 256, 0, stream>>>(qkv_w, wqkv, 1536 * 512);
  cvt_k<<<(512 * 512 + 255) / 256, 256, 0, stream>>>(proj_w, wproj, 512 * 512);
  cvt_k<<<(2048 * 512 + 255) / 256, 256, 0, stream>>>(fc1_w, wfc1, 2048 * 512);
  cvt_k<<<(512 * 2048 + 255) / 256, 256, 0, stream>>>(fc2_w, wfc2, 512 * 2048);
  cpb_k<<<15, 256, 0, stream>>>(ctab, cpb_w1, cpb_b1, cpb_w2, t2);
  bias_k<<<256, 256, 0, stream>>>(t2, rpi, b16);
  scale_k<<<1, 64, 0, stream>>>(lscale, scbuf);

  // x -> xw (bf16, shifted-window order)
  xw_k<<<MTOT * 64 / 256, 256, 0, stream>>>(x, xw);
  // QKV -> q/k/v [b_][h][n][d] bf16
  gemm128_k<0><<<dim3(1536 / 128, MTOT / 128), 256, 0, stream>>>(
      xw, wqkv, nullptr, q_bias, v_bias, q_buf, k_buf, v_buf, nullptr, nullptr, 512);
  // attention (fused cosine norm)
  attn_k<<<BWIN * HEADS, 64, 0, stream>>>(q_buf, k_buf, v_buf, b16, scbuf, amask, attn_out);
  // proj (window reverse fused) -> proj_out fp32, original token order
  gemm128_k<1><<<dim3(512 / 128, MTOT / 128), 256, 0, stream>>>(
      attn_out, wproj, proj_b, nullptr, nullptr, nullptr, nullptr, nullptr, proj_out, nullptr, 512);
  // x1 = x + LN1(proj_out)  -> d_out (fp32) + x1b (bf16)
  ln_res_k<<<MTOT / 4, 256, 0, stream>>>(x, proj_out, n1g, n1b, outp, x1b);
  // MLP in two row-halves (hidden buffer reuse, 128 MiB)
  for (int half = 0; half < 2; half++) {
    const u16* a1 = x1b + (size_t)half * (MTOT / 2) * CCH;
    u16* m1 = mlp_out + (size_t)half * (MTOT / 2) * CCH;
    gemm128_k<2><<<dim3(HIDN / 128, MTOT / 2 / 128), 256, 0, stream>>>(
        a1, wfc1, fc1_b, nullptr, nullptr, nullptr, nullptr, nullptr, nullptr, hid, 512);
    gemm128_k<3><<<dim3(512 / 128, MTOT / 2 / 128), 256, 0, stream>>>(
        hid, wfc2, fc2_b, nullptr, nullptr, nullptr, nullptr, nullptr, nullptr, m1, 2048);
  }
  // out = x1 + LN2(mlp)
  ln_fin_k<<<MTOT / 4, 256, 0, stream>>>(mlp_out, n2g, n2b, outp);
}

// Round 3
// 1209.539 us; speedup vs baseline: 1.4861x; 1.1266x over previous
//
#include <hip/hip_runtime.h>
#include <hip/hip_bf16.h>
#include <math.h>

// ---- problem constants ----
#define BB     16
#define HH     64
#define WWID   64
#define CCH    512
#define HEADS  16
#define NTOK   64
#define DDIM   32
#define NWIN   64
#define LL     (HH*WWID)       // 4096
#define MTOT   (BB*LL)         // 65536 rows
#define BWIN   (BB*NWIN)       // 1024 windows
#define HIDN   2048
#define SHIFT_ 4

typedef unsigned short u16;
using bf16x8 = __attribute__((ext_vector_type(8))) short;   // 8 bf16 (4 VGPRs)
using f32x4  = __attribute__((ext_vector_type(4))) float;
using f32x16 = __attribute__((ext_vector_type(16))) float;

__device__ __forceinline__ u16 f2bf(float f) {
  union { float f; unsigned u; } v; v.f = f;
  unsigned r = v.u + 0x7fffu + ((v.u >> 16) & 1u);   // RNE
  return (u16)(r >> 16);
}
__device__ __forceinline__ float bf2f(unsigned h) {
  union { unsigned u; float f; } v; v.u = h << 16;
  return v.f;
}

__device__ __forceinline__ void gload16(const void* g, void* l) {
  __builtin_amdgcn_global_load_lds((const __attribute__((address_space(1))) void*)g,
                                   (__attribute__((address_space(3))) void*)l, 16, 0, 0);
}

// shifted-window mapping: windowed token (b_, n) -> original row index in x
__device__ __forceinline__ int win2orig(int b_, int n) {
  int b = b_ >> 6, wi = b_ & 63;
  int hs = (wi >> 3) * 8 + (n >> 3);
  int ws = (wi & 7) * 8 + (n & 7);
  int hq = (hs + SHIFT_) & 63;
  int wq = (ws + SHIFT_) & 63;
  return b * LL + hq * WWID + wq;
}

// ---------------- tiny setup kernels ----------------
__global__ void cvt_k(const float* __restrict__ s, u16* __restrict__ d, int n) {
  int i = blockIdx.x * 256 + threadIdx.x;
  if (i < n) d[i] = f2bf(s[i]);
}

__global__ void cpb_k(const float* __restrict__ ct, const float* __restrict__ w1,
                      const float* __restrict__ b1, const float* __restrict__ w2,
                      float* __restrict__ t2) {
  int t = blockIdx.x * 256 + threadIdx.x;
  if (t >= 225 * 16) return;
  int rr = t >> 4, h = t & 15;
  float c0 = ct[rr * 2], c1 = ct[rr * 2 + 1];
  float acc = 0.f;
  for (int j = 0; j < 512; j++) {
    float hv = fmaxf(w1[j * 2] * c0 + w1[j * 2 + 1] * c1 + b1[j], 0.f);
    acc += hv * w2[h * 512 + j];
  }
  t2[t] = acc;
}

__global__ void bias_k(const float* __restrict__ t2, const int* __restrict__ rpi,
                       float* __restrict__ b16) {
  int t = blockIdx.x * 256 + threadIdx.x;   // h*4096 + n*64 + m
  int nm = t & 4095;
  int h = t >> 12;
  float v = t2[rpi[nm] * 16 + h];
  b16[t] = 16.0f / (1.0f + __expf(-v));
}

__global__ void scale_k(const float* __restrict__ ls, float* __restrict__ sc) {
  int t = threadIdx.x;
  if (t < HEADS) sc[t] = __expf(fminf(ls[t], 4.6051701859880914f)); // ln(100)
}

// x (fp32) -> xw (bf16) in shifted-window token order [b_*64+n][512]
__global__ __launch_bounds__(256) void xw_k(const float* __restrict__ x, u16* __restrict__ xw) {
  int t = blockIdx.x * 256 + threadIdx.x;
  int row = t >> 6;
  int col = (t & 63) * 8;
  const float* src = x + (size_t)win2orig(row >> 6, row & 63) * CCH + col;
  float4 a = *(const float4*)src;
  float4 b = *(const float4*)(src + 4);
  u16 o[8] = {f2bf(a.x), f2bf(a.y), f2bf(a.z), f2bf(a.w),
              f2bf(b.x), f2bf(b.y), f2bf(b.z), f2bf(b.w)};
  *(uint4*)(xw + (size_t)row * CCH + col) = *(const uint4*)o;
}

// ---------------- MFMA GEMM, 256x128 block tile, 32x32x16 MFMA ----------------
// A bf16 [M][K], B bf16 [N][K] -> C = A @ B^T.  4 waves, wave tile 128x64.
// LDS k-chunk XOR-swizzle (chunk ^= row&3) applied on global addr at staging.
// XCD swizzle: lin%8 -> XCD, contiguous M-chunk per XCD for A-tile L2 reuse.
// MODE 0: QKV (epi: +q/v bias, scatter to [b_][h][n][d] bf16)
// MODE 1: proj (epi: +proj_b, bf16 scatter to original token order)
// MODE 2: fc1  (epi: +fc1_b, exact GELU, bf16 ld=HIDN)
// MODE 3: fc2  (epi: +fc2_b, bf16 ld=CCH)
template<int MODE, int NBN>
__global__ __launch_bounds__(256, 2) void gemm256_k(
    const u16* __restrict__ A, const u16* __restrict__ Bw,
    const float* __restrict__ bias,
    const float* __restrict__ qbias, const float* __restrict__ vbias,
    u16* __restrict__ o0, u16* __restrict__ o1, u16* __restrict__ o2,
    int K, int mchunk)
{
  __shared__ __align__(16) u16 As[256 * 32];   // 16 KB
  __shared__ __align__(16) u16 Bs[128 * 32];   // 8 KB
  const int t = threadIdx.x;
  const int lin = blockIdx.x;
  const int xcd = lin & 7;
  const int j = lin >> 3;
  const int m0 = (xcd * mchunk + j / NBN) * 256;
  const int n0 = (j % NBN) * 128;
  const int lane = t & 63;
  const int wv = t >> 6;
  const int wm = (wv & 1) * 128;
  const int wn = (wv >> 1) * 64;
  const int l31 = lane & 31;
  const int khalf = lane >> 5;   // 0/1
  const int sw = lane & 3;       // row&3 for fragment rows

  // staging pointers: LDS chunk c = i*256 + t; row = c>>2, lds k-chunk = c&3,
  // global k-chunk = (c&3) ^ (row&3); row&3 = (t>>2)&3 for all i.
  const int swcol = (((t & 3) ^ ((t >> 2) & 3)) * 8);
  const u16* aP[4]; char* aL[4];
  #pragma unroll
  for (int i = 0; i < 4; i++) {
    aP[i] = A + (size_t)(m0 + i * 64 + (t >> 2)) * K + swcol;
    aL[i] = (char*)As + i * 4096 + wv * 1024;
  }
  const u16* bP[2]; char* bL[2];
  #pragma unroll
  for (int i = 0; i < 2; i++) {
    bP[i] = Bw + (size_t)(n0 + i * 64 + (t >> 2)) * K + swcol;
    bL[i] = (char*)Bs + i * 4096 + wv * 1024;
  }

  f32x16 acc[4][2] = {};

  for (int k0 = 0; k0 < K; k0 += 32) {
    #pragma unroll
    for (int i = 0; i < 4; i++) gload16(aP[i] + k0, aL[i]);
    #pragma unroll
    for (int i = 0; i < 2; i++) gload16(bP[i] + k0, bL[i]);
    __syncthreads();
    #pragma unroll
    for (int ks = 0; ks < 2; ks++) {
      const int kc = (ks * 2 + khalf) ^ sw;   // swizzled k-chunk
      bf16x8 af[4], bf[2];
      #pragma unroll
      for (int mt = 0; mt < 4; mt++)
        af[mt] = *(const bf16x8*)&As[(wm + mt * 32 + l31) * 32 + kc * 8];
      #pragma unroll
      for (int nt = 0; nt < 2; nt++)
        bf[nt] = *(const bf16x8*)&Bs[(wn + nt * 32 + l31) * 32 + kc * 8];
      #pragma unroll
      for (int mt = 0; mt < 4; mt++)
        #pragma unroll
        for (int nt = 0; nt < 2; nt++)
          acc[mt][nt] = __builtin_amdgcn_mfma_f32_32x32x16_bf16(af[mt], bf[nt], acc[mt][nt], 0, 0, 0);
    }
    __syncthreads();
  }

  // epilogue; 32x32 C/D: col = lane&31, row = (reg&3) + 8*(reg>>2) + 4*(lane>>5)
  const int part = n0 >> 9;   // MODE 0 only (tile never spans q/k/v parts)
  const u16* dummy = nullptr; (void)dummy;
  u16* qkvdst = (MODE == 0) ? (part == 0 ? o0 : (part == 1 ? o1 : o2)) : o0;
  #pragma unroll
  for (int mt = 0; mt < 4; mt++)
    #pragma unroll
    for (int nt = 0; nt < 2; nt++)
      #pragma unroll
      for (int r = 0; r < 16; r++) {
        int grow = m0 + wm + mt * 32 + (r & 3) + 8 * (r >> 2) + 4 * khalf;
        int gc = n0 + wn + nt * 32 + l31;
        float v = acc[mt][nt][r];
        if (MODE == 0) {
          int cc = gc & 511;
          if (part == 0) v += qbias[cc];
          else if (part == 2) v += vbias[cc];
          int b_ = grow >> 6, n = grow & 63;
          int hh = cc >> 5, dd = cc & 31;
          qkvdst[(((size_t)b_ * HEADS + hh) * NTOK + n) * DDIM + dd] = f2bf(v);
        } else if (MODE == 1) {
          v += bias[gc];
          o0[(size_t)win2orig(grow >> 6, grow & 63) * CCH + gc] = f2bf(v);
        } else if (MODE == 2) {
          v += bias[gc];
          float g = 0.5f * v * (1.0f + erff(v * 0.70710678118654752f));
          o0[(size_t)grow * HIDN + gc] = f2bf(g);
        } else {
          v += bias[gc];
          o0[(size_t)grow * CCH + gc] = f2bf(v);
        }
      }
}

// ---------------- attention: one wave per (window, head), in-register softmax ----------------
__global__ __launch_bounds__(64) void attn_k(
    const u16* __restrict__ qb, const u16* __restrict__ kb, const u16* __restrict__ vb,
    const float* __restrict__ bias16, const float* __restrict__ scale,
    const float* __restrict__ amask, u16* __restrict__ attn_out)
{
  __shared__ u16 Pmat[64][72];   // bf16 P (unnormalized), 144B rows (16B-aligned)
  __shared__ u16 vT[32][72];     // V transposed [d][tok]

  int bh = blockIdx.x;
  int b_ = bh >> 4, h = bh & 15;
  int wi = b_ & 63;
  int lane = threadIdx.x;
  int l15 = lane & 15, quad = lane >> 4;
  const u16* qs = qb + (size_t)bh * (NTOK * DDIM);
  const u16* ks = kb + (size_t)bh * (NTOK * DDIM);
  const u16* vs = vb + (size_t)bh * (NTOK * DDIM);

  bf16x8 qf[4], kf[4];
  #pragma unroll
  for (int mt = 0; mt < 4; mt++) {
    qf[mt] = *(const bf16x8*)(qs + (mt * 16 + l15) * DDIM + quad * 8);
    kf[mt] = *(const bf16x8*)(ks + (mt * 16 + l15) * DDIM + quad * 8);
  }
  // fused cosine normalization: lanes {l15, +16, +32, +48} share a row
  #pragma unroll
  for (int mt = 0; mt < 4; mt++) {
    float sq = 0.f, sk = 0.f;
    #pragma unroll
    for (int jj = 0; jj < 8; jj++) {
      float a = bf2f((u16)qf[mt][jj]); sq += a * a;
      float b = bf2f((u16)kf[mt][jj]); sk += b * b;
    }
    sq += __shfl_xor(sq, 16); sq += __shfl_xor(sq, 32);
    sk += __shfl_xor(sk, 16); sk += __shfl_xor(sk, 32);
    float iq = 1.f / fmaxf(sqrtf(sq), 1e-12f);
    float ik = 1.f / fmaxf(sqrtf(sk), 1e-12f);
    #pragma unroll
    for (int jj = 0; jj < 8; jj++) {
      qf[mt][jj] = (short)f2bf(bf2f((u16)qf[mt][jj]) * iq);
      kf[mt][jj] = (short)f2bf(bf2f((u16)kf[mt][jj]) * ik);
    }
  }
  // S = qn @ kn^T (in registers)
  f32x4 s[4][4];
  #pragma unroll
  for (int mt = 0; mt < 4; mt++)
    #pragma unroll
    for (int nt = 0; nt < 4; nt++) {
      f32x4 c = {0.f, 0.f, 0.f, 0.f};
      s[mt][nt] = __builtin_amdgcn_mfma_f32_16x16x32_bf16(qf[mt], kf[nt], c, 0, 0, 0);
    }
  // stage V^T
  #pragma unroll
  for (int d8 = 0; d8 < 4; d8++) {
    bf16x8 vv = *(const bf16x8*)(vs + lane * DDIM + d8 * 8);
    #pragma unroll
    for (int jj = 0; jj < 8; jj++) vT[d8 * 8 + jj][lane] = (u16)vv[jj];
  }

  // in-register softmax: row = mt*16+quad*4+i (16 lanes/row across l15)
  float sc = scale[h];
  float rinv[4][4];
  const float* bbase = bias16 + (size_t)h * 4096;
  const float* mbase = amask + (size_t)wi * 4096;
  #pragma unroll
  for (int mt = 0; mt < 4; mt++) {
    #pragma unroll
    for (int i = 0; i < 4; i++) {
      int row = mt * 16 + quad * 4 + i;
      const float* bro = bbase + row * 64;
      const float* mro = mbase + row * 64;
      float p[4];
      float mx = -1e30f;
      #pragma unroll
      for (int nt = 0; nt < 4; nt++) {
        int col = nt * 16 + l15;
        float vv = s[mt][nt][i] * sc + bro[col] + mro[col];
        p[nt] = vv;
        mx = fmaxf(mx, vv);
      }
      mx = fmaxf(mx, __shfl_xor(mx, 1));
      mx = fmaxf(mx, __shfl_xor(mx, 2));
      mx = fmaxf(mx, __shfl_xor(mx, 4));
      mx = fmaxf(mx, __shfl_xor(mx, 8));
      float sum = 0.f;
      #pragma unroll
      for (int nt = 0; nt < 4; nt++) {
        float e = __expf(p[nt] - mx);
        p[nt] = e;
        sum += e;
      }
      sum += __shfl_xor(sum, 1);
      sum += __shfl_xor(sum, 2);
      sum += __shfl_xor(sum, 4);
      sum += __shfl_xor(sum, 8);
      rinv[mt][i] = 1.f / sum;
      #pragma unroll
      for (int nt = 0; nt < 4; nt++)
        Pmat[row][nt * 16 + l15] = f2bf(p[nt]);
    }
  }
  __syncthreads();

  // O = P @ V (1/sum folded into epilogue)
  f32x4 oacc[4][2] = {};
  #pragma unroll
  for (int ks2 = 0; ks2 < 2; ks2++) {
    bf16x8 pf[4], vf[2];
    #pragma unroll
    for (int mt = 0; mt < 4; mt++)
      pf[mt] = *(const bf16x8*)&Pmat[mt * 16 + l15][ks2 * 32 + quad * 8];
    #pragma unroll
    for (int nt = 0; nt < 2; nt++)
      vf[nt] = *(const bf16x8*)&vT[nt * 16 + l15][ks2 * 32 + quad * 8];
    #pragma unroll
    for (int mt = 0; mt < 4; mt++)
      #pragma unroll
      for (int nt = 0; nt < 2; nt++)
        oacc[mt][nt] = __builtin_amdgcn_mfma_f32_16x16x32_bf16(pf[mt], vf[nt], oacc[mt][nt], 0, 0, 0);
  }
  #pragma unroll
  for (int mt = 0; mt < 4; mt++)
    #pragma unroll
    for (int nt = 0; nt < 2; nt++)
      #pragma unroll
      for (int i = 0; i < 4; i++) {
        int n = mt * 16 + quad * 4 + i;
        int d = nt * 16 + l15;
        float val = oacc[mt][nt][i] * rinv[mt][i];
        attn_out[(size_t)(b_ * 64 + n) * CCH + h * DDIM + d] = f2bf(val);
      }
}

// ---------------- LayerNorm + residual kernels (one wave per row) ----------------
__global__ __launch_bounds__(256) void ln_res_k(
    const float* __restrict__ xin, const u16* __restrict__ pin,
    const float* __restrict__ gam, const float* __restrict__ bet,
    float* __restrict__ x1f, u16* __restrict__ x1b)
{
  int row = blockIdx.x * 4 + (threadIdx.x >> 6);
  int lane = threadIdx.x & 63;
  size_t base = (size_t)row * CCH + lane * 8;
  uint4 u = *(const uint4*)(pin + base);
  unsigned w[4] = {u.x, u.y, u.z, u.w};
  float pv[8];
  #pragma unroll
  for (int j = 0; j < 4; j++) {
    pv[j * 2] = bf2f(w[j] & 0xffffu);
    pv[j * 2 + 1] = bf2f(w[j] >> 16);
  }
  const float* xr = xin + base;
  float s = 0.f, sq = 0.f;
  #pragma unroll
  for (int j = 0; j < 8; j++) { s += pv[j]; sq += pv[j] * pv[j]; }
  #pragma unroll
  for (int o = 32; o > 0; o >>= 1) { s += __shfl_xor(s, o, 64); sq += __shfl_xor(sq, o, 64); }
  float mean = s * (1.0f / 512.0f);
  float var = sq * (1.0f / 512.0f) - mean * mean;
  float rstd = rsqrtf(var + 1e-5f);
  #pragma unroll
  for (int j = 0; j < 8; j++) {
    int c = lane * 8 + j;
    float val = xr[j] + (pv[j] - mean) * rstd * gam[c] + bet[c];
    x1f[base + j] = val;
    x1b[base + j] = f2bf(val);
  }
}

__global__ __launch_bounds__(256) void ln_fin_k(
    const u16* __restrict__ mlp, const float* __restrict__ gam,
    const float* __restrict__ bet, float* __restrict__ io)
{
  int row = blockIdx.x * 4 + (threadIdx.x >> 6);
  int lane = threadIdx.x & 63;
  size_t base = (size_t)row * CCH + lane * 8;
  uint4 u = *(const uint4*)(mlp + base);
  unsigned w[4] = {u.x, u.y, u.z, u.w};
  float pv[8];
  #pragma unroll
  for (int j = 0; j < 4; j++) {
    pv[j * 2] = bf2f(w[j] & 0xffffu);
    pv[j * 2 + 1] = bf2f(w[j] >> 16);
  }
  float s = 0.f, sq = 0.f;
  #pragma unroll
  for (int j = 0; j < 8; j++) { s += pv[j]; sq += pv[j] * pv[j]; }
  #pragma unroll
  for (int o = 32; o > 0; o >>= 1) { s += __shfl_xor(s, o, 64); sq += __shfl_xor(sq, o, 64); }
  float mean = s * (1.0f / 512.0f);
  float var = sq * (1.0f / 512.0f) - mean * mean;
  float rstd = rsqrtf(var + 1e-5f);
  #pragma unroll
  for (int j = 0; j < 8; j++) {
    int c = lane * 8 + j;
    io[base + j] = io[base + j] + (pv[j] - mean) * rstd * gam[c] + bet[c];
  }
}

// ---------------- launcher ----------------
#define OFF_Q     ((size_t)0)
#define OFF_K     ((size_t)67108864)
#define OFF_V     ((size_t)134217728)
#define OFF_ATTN  ((size_t)201326592)
#define OFF_X1B   ((size_t)268435456)
#define OFF_WQKV  ((size_t)335544320)
#define OFF_WPROJ ((size_t)337117184)
#define OFF_WFC1  ((size_t)337641472)
#define OFF_WFC2  ((size_t)339738624)
#define OFF_T2    ((size_t)341835776)
#define OFF_B16   ((size_t)341852160)
#define OFF_SC    ((size_t)342114304)

extern "C" void kernel_launch(void* const* d_in, const int* in_sizes, int n_in,
                              void* d_out, int out_size, void* d_ws, size_t ws_size,
                              hipStream_t stream) {
  const float* x        = (const float*)d_in[0];
  const float* qkv_w    = (const float*)d_in[1];
  const float* q_bias   = (const float*)d_in[2];
  const float* v_bias   = (const float*)d_in[3];
  const float* lscale   = (const float*)d_in[4];
  const float* cpb_w1   = (const float*)d_in[5];
  const float* cpb_b1   = (const float*)d_in[6];
  const float* cpb_w2   = (const float*)d_in[7];
  const float* proj_w   = (const float*)d_in[8];
  const float* proj_b   = (const float*)d_in[9];
  const float* n1g      = (const float*)d_in[10];
  const float* n1b      = (const float*)d_in[11];
  const float* n2g      = (const float*)d_in[12];
  const float* n2b      = (const float*)d_in[13];
  const float* fc1_w    = (const float*)d_in[14];
  const float* fc1_b    = (const float*)d_in[15];
  const float* fc2_w    = (const float*)d_in[16];
  const float* fc2_b    = (const float*)d_in[17];
  const float* ctab     = (const float*)d_in[18];
  const float* amask    = (const float*)d_in[19];
  const int*   rpi      = (const int*)d_in[20];

  char* ws = (char*)d_ws;
  float* outp = (float*)d_out;

  u16*   q_buf    = (u16*)(ws + OFF_Q);
  u16*   k_buf    = (u16*)(ws + OFF_K);
  u16*   v_buf    = (u16*)(ws + OFF_V);
  u16*   proj_out = (u16*)(ws + OFF_Q);     // reuse R0 (bf16 now)
  u16*   hid      = (u16*)(ws + OFF_Q);     // reuse R0 (half-batch)
  u16*   xw       = (u16*)(ws + OFF_ATTN);  // R1 (dead after QKV gemm)
  u16*   attn_out = (u16*)(ws + OFF_ATTN);
  u16*   mlp_out  = (u16*)(ws + OFF_ATTN);
  u16*   x1b      = (u16*)(ws + OFF_X1B);
  u16*   wqkv     = (u16*)(ws + OFF_WQKV);
  u16*   wproj    = (u16*)(ws + OFF_WPROJ);
  u16*   wfc1     = (u16*)(ws + OFF_WFC1);
  u16*   wfc2     = (u16*)(ws + OFF_WFC2);
  float* t2       = (float*)(ws + OFF_T2);
  float* b16      = (float*)(ws + OFF_B16);
  float* scbuf    = (float*)(ws + OFF_SC);

  cvt_k<<<(1536 * 512 + 255) / 256, 256, 0, stream>>>(qkv_w, wqkv, 1536 * 512);
  cvt_k<<<(512 * 512 + 255) / 256, 256, 0, stream>>>(proj_w, wproj, 512 * 512);
  cvt_k<<<(2048 * 512 + 255) / 256, 256, 0, stream>>>(fc1_w, wfc1, 2048 * 512);
  cvt_k<<<(512 * 2048 + 255) / 256, 256, 0, stream>>>(fc2_w, wfc2, 512 * 2048);
  cpb_k<<<15, 256, 0, stream>>>(ctab, cpb_w1, cpb_b1, cpb_w2, t2);
  bias_k<<<256, 256, 0, stream>>>(t2, rpi, b16);
  scale_k<<<1, 64, 0, stream>>>(lscale, scbuf);

  // x -> xw (bf16, shifted-window order)
  xw_k<<<MTOT * 64 / 256, 256, 0, stream>>>(x, xw);
  // QKV: M=65536 (256 m-tiles), N=1536 (12 n-tiles)
  gemm256_k<0, 12><<<256 * 12, 256, 0, stream>>>(
      xw, wqkv, nullptr, q_bias, v_bias, q_buf, k_buf, v_buf, 512, 32);
  // attention (fused cosine norm, in-register softmax)
  attn_k<<<BWIN * HEADS, 64, 0, stream>>>(q_buf, k_buf, v_buf, b16, scbuf, amask, attn_out);
  // proj: N=512 (4 n-tiles), bf16 out, window-reverse fused
  gemm256_k<1, 4><<<256 * 4, 256, 0, stream>>>(
      attn_out, wproj, proj_b, nullptr, nullptr, proj_out, nullptr, nullptr, 512, 32);
  // x1 = x + LN1(proj_out)
  ln_res_k<<<MTOT / 4, 256, 0, stream>>>(x, proj_out, n1g, n1b, outp, x1b);
  // MLP in two row-halves
  for (int half = 0; half < 2; half++) {
    const u16* a1 = x1b + (size_t)half * (MTOT / 2) * CCH;
    u16* m1 = mlp_out + (size_t)half * (MTOT / 2) * CCH;
    gemm256_k<2, 16><<<128 * 16, 256, 0, stream>>>(
        a1, wfc1, fc1_b, nullptr, nullptr, hid, nullptr, nullptr, 512, 16);
    gemm256_k<3, 4><<<128 * 4, 256, 0, stream>>>(
        hid, wfc2, fc2_b, nullptr, nullptr, m1, nullptr, nullptr, 2048, 16);
  }
  // out = x1 + LN2(mlp)
  ln_fin_k<<<MTOT / 4, 256, 0, stream>>>(mlp_out, n2g, n2b, outp);
}